// Round 7
// baseline (55.908 us; speedup 1.0000x reference)
//
#include <hip/hip_runtime.h>
#include <math.h>

// LIFNeuronFDE: fractional-order LIF with Grunwald-Letnikov memory.
//   v^{k+1} = 2*(I_k - v^k) - sum_{j=0}^{k} c_{k+1-j} v^{(j)},  v^{(0)} = v0
//   spike_k = sigmoid(5*(v^{k+1} - 1))
// T=32, B=32, N=32768.  Linear-map form: v_{k+1} = b[k]*v0 + sum_j a[k][j] I_j.
//
// R6 lesson: gather form CSE'd (double)If[j] across rows -> ~64 fp64 temps
// live whole-kernel -> AGPR split (occupancy 28.8%) + ~1000 accvgpr moves
// (VALU time 2x fp64 ideal). Fix: 3-phase SCATTER. Rows blocked [0,11),
// [11,22), [22,32); per block loop j ascending, cvt If[j] ONCE, scatter
// s[k] += a[k][j]*Id, emit row j when complete. Per-accumulator fma order
// identical to R6 -> bitwise-same trajectory (margin is thin: 0.0176/0.02).
// Peak regs ~125 -> no AGPR split, 3-4 waves/SIMD. Loads prefetched one
// phase ahead, stores spread. Outer j loops template-recursive (R2: nested
// pragma unroll with variable inner trip silently fails).

#define T_STEPS 32
#define BN (32 * 32768)              // B*N = 1,048,576 elements
#define PAIRS (BN / 2)               // 524,288 float2 work items
#define RB1 11                       // phase row boundaries
#define RB2 22

struct LinMap {
    double a[T_STEPS][T_STEPS];      // a[k][j]: coeff of I_j in v_{k+1} (j<=k)
    double b[T_STEPS];               // b[k]:    coeff of v0  in v_{k+1}
};

constexpr LinMap make_linmap() {
    double c[T_STEPS + 1] = {};
    c[0] = 1.0;
    for (int j = 1; j <= T_STEPS; ++j) c[j] = c[j - 1] * (1.0 - 1.5 / (double)j);

    double vc[T_STEPS + 1][T_STEPS + 1] = {};   // coeff of basis m in v_k
    vc[0][0] = 1.0;                              // m=0 -> v0, m=1+j -> I_j

    LinMap r{};
    for (int k = 0; k < T_STEPS; ++k) {
        for (int m = 0; m <= T_STEPS; ++m) {
            double acc = -2.0 * vc[k][m];
            for (int j = 0; j <= k; ++j) acc -= c[k + 1 - j] * vc[j][m];
            vc[k + 1][m] = acc;
        }
        vc[k + 1][1 + k] += 2.0;
        r.b[k] = vc[k + 1][0];
        for (int j = 0; j < T_STEPS; ++j) r.a[k][j] = vc[k + 1][1 + j];
    }
    return r;
}

constexpr LinMap CM = make_linmap();

// Stage If[J0..J1) — constant trip, literal indices.
template<int J0, int J1>
__device__ __forceinline__ void stage(float2 (&If)[T_STEPS],
                                      const float2* __restrict__ I2, const int idx)
{
    #pragma unroll
    for (int j = J0; j < J1; ++j) If[j] = I2[(size_t)j * PAIRS + idx];
}

// Init s[K0..KEND) = b[k]*v0 — first op of each accumulator (same as R6).
template<int K0, int KEND>
__device__ __forceinline__ void init_s(double (&sx)[T_STEPS], double (&sy)[T_STEPS],
                                       const double v0x, const double v0y)
{
    #pragma unroll
    for (int k = K0; k < KEND; ++k) { sx[k] = CM.b[k] * v0x; sy[k] = CM.b[k] * v0y; }
}

// Scatter phase for rows [K0,KEND): iterate j = 0..KEND-1 (template-literal),
// cvt If[j] once, update s[k] for k in [max(j,K0),KEND), emit row j when done.
template<int J, int K0, int KEND>
__device__ __forceinline__ void scatter_phase(const float2 (&If)[T_STEPS],
                                              double (&sx)[T_STEPS], double (&sy)[T_STEPS],
                                              float2* __restrict__ out2, const int idx)
{
    if constexpr (J < KEND) {
        const double Ix = (double)If[J].x;   // ONE cvt per (j, phase)
        const double Iy = (double)If[J].y;
        constexpr int kst = (J > K0) ? J : K0;
        #pragma unroll
        for (int k = kst; k < KEND; ++k) {   // ascending j per accumulator
            sx[k] = fma(CM.a[k][J], Ix, sx[k]);
            sy[k] = fma(CM.a[k][J], Iy, sy[k]);
        }
        if constexpr (J >= K0) {             // row J complete -> emit, s[J] dies
            const float ax = (float)(-5.0 * (sx[J] - 1.0));
            const float ay = (float)(-5.0 * (sy[J] - 1.0));
            out2[(size_t)J * PAIRS + idx] =
                make_float2(__builtin_amdgcn_rcpf(1.0f + __expf(ax)),
                            __builtin_amdgcn_rcpf(1.0f + __expf(ay)));
        }
        scatter_phase<J + 1, K0, KEND>(If, sx, sy, out2, idx);
    }
}

__global__ __launch_bounds__(256) void lif_fde_kernel(
    const float* __restrict__ I,
    const float* __restrict__ v0,
    float* __restrict__ out)
{
    const int idx = blockIdx.x * blockDim.x + threadIdx.x;   // [0, PAIRS)

    const float2* __restrict__ I2   = (const float2*)I;
    const float2* __restrict__ v02  = (const float2*)v0;
    float2* __restrict__       out2 = (float2*)out;

    float2 If[T_STEPS];
    double sx[T_STEPS], sy[T_STEPS];

    stage<0, RB1>(If, I2, idx);          // phase-A inputs
    stage<RB1, RB2>(If, I2, idx);        // prefetch phase B

    const float2 v0f = v02[idx];
    const double v0x = (double)v0f.x;
    const double v0y = (double)v0f.y;

    // Phase A: rows [0,11)
    init_s<0, RB1>(sx, sy, v0x, v0y);
    scatter_phase<0, 0, RB1>(If, sx, sy, out2, idx);

    stage<RB2, T_STEPS>(If, I2, idx);    // prefetch phase C

    // Phase B: rows [11,22)
    init_s<RB1, RB2>(sx, sy, v0x, v0y);
    scatter_phase<0, RB1, RB2>(If, sx, sy, out2, idx);

    // Phase C: rows [22,32)
    init_s<RB2, T_STEPS>(sx, sy, v0x, v0y);
    scatter_phase<0, RB2, T_STEPS>(If, sx, sy, out2, idx);
}

extern "C" void kernel_launch(void* const* d_in, const int* in_sizes, int n_in,
                              void* d_out, int out_size, void* d_ws, size_t ws_size,
                              hipStream_t stream) {
    const float* I  = (const float*)d_in[0];   // (T, B, N) fp32
    const float* v0 = (const float*)d_in[1];   // (B, N) fp32
    float* out = (float*)d_out;                // (T, B, N) fp32

    dim3 block(256);
    dim3 grid(PAIRS / 256);                    // 2048 blocks, exact fit
    lif_fde_kernel<<<grid, block, 0, stream>>>(I, v0, out);
}